// Round 10
// baseline (219.472 us; speedup 1.0000x reference)
//
#include <hip/hip_runtime.h>

// InternalInteraction: out[b,j,d] = sum_i [ relu((x_i*x_j)@W1^T + b1) @ W2^T + b2 ]
// Factored: hsum[b,j,h] = sum_i relu((x_i*x_j)@W1^T + b1); out = hsum@W2^T + 16*b2.
// B=2048, A=16, D=128, H=512. Storage fp32; MFMA in bf16.
//
// Round-13 structure (vs round-12):
//  - POST-MORTEM r12: switch-DPP lost 15us to the switch itself (blocks
//    cross-iteration af prefetch hoisting), not to DPP. Rotation vehicle
//    must be BRANCH-FREE in steady state -> Horner (r9 structure).
//  - r9's Horner failed ONLY on registers (+16 srot > 128 unified budget
//    at 16 waves/CU). This round frees exactly 16 at r8's geometry:
//      (a) bias4 16->8 regs: b1 packed as bf16-hi pairs, unpacked with
//          4 shifts per n per tile (+144 VALU/wave; bias bf16 rounding
//          ~1e-3, swamped by the existing hsum->bf16 cast, tol 0.0625)
//      (b) af 16->8 regs: explicit 2-buffer rotation interleaved with
//          the four MFMA groups (load kk2 after group0, kk3 after group1)
//    Net register delta vs r8: -8 -8 +16 = 0 (r8's fit is proven).
//  - DPP-HORNER: srot = v_dlt + ror1(srot) for dlt=7..1 (uniform if),
//    then hsum += ror1(srot). Replaces 112 ds_bpermute/wave (LDS pipe,
//    ~5.4k cyc/block) with 112 fused VALU dpp-adds. Same values summed.
//  - Everything else = r8: 512 thr / 8 waves / 64 h per wave, (512,4),
//    9 shift tiles, swapped-operand GEMM1 (C rows=h, cols=j), unroll-1,
//    f32 xs staging, hs aliasing dead ps, 4 barriers/block.

#define BATCH 2048
#define AA 16
#define DD 128
#define HH 512

typedef __bf16 bf16;
typedef bf16  bf16x4 __attribute__((ext_vector_type(4)));
typedef bf16  bf16x8 __attribute__((ext_vector_type(8)));
typedef float f32x4  __attribute__((ext_vector_type(4)));

__device__ inline f32x4 splat4(float v) { f32x4 r = {v, v, v, v}; return r; }

// rotate within each 16-lane row: lane j takes lane (j-1)&15 (DPP row_ror:1)
// validated on HW by r10/r11 (passed with this exact ctrl)
__device__ __forceinline__ float ror1_f32(float v) {
    return __int_as_float(__builtin_amdgcn_mov_dpp(
        __float_as_int(v), 0x121, 0xF, 0xF, false));
}

// ---- prologue: fp32 -> bf16 weight conversion into d_ws ----
// ws layout: [0, 65536)  = W1b (512x128 row-major bf16)
//            [65536, ..) = W2b (128x512 row-major bf16)
__global__ __launch_bounds__(256, 1)
void convert_weights(const float* __restrict__ W1,
                     const float* __restrict__ W2,
                     bf16* __restrict__ wsb)
{
    int t = blockIdx.x * 256 + threadIdx.x;      // 0..32767, 4 elems each
    f32x4 v = (t < 16384) ? *(const f32x4*)(W1 + 4 * t)
                          : *(const f32x4*)(W2 + 4 * (t - 16384));
    bf16x4 o;
    o[0] = (bf16)v[0]; o[1] = (bf16)v[1]; o[2] = (bf16)v[2]; o[3] = (bf16)v[3];
    *(bf16x4*)(wsb + 4 * t) = o;
}

// One block per batch. 512 threads = 8 waves; wave w owns H cols [w*64, w*64+64).
__global__ __launch_bounds__(512, 4)
void interact_kernel(const float* __restrict__ x,    // [B, A, D] fp32
                     const bf16*  __restrict__ W1b,  // [H, D] bf16 (from ws)
                     const float* __restrict__ b1,   // [H]
                     const bf16*  __restrict__ W2b,  // [D, H] bf16 (from ws)
                     const float* __restrict__ b2,   // [D]
                     float* __restrict__ out)        // [B, A, D] fp32
{
    // xs: x_b in f32, row stride 136 (544 B)
    __shared__ float xs[16][136];                               // 8704 B
    // ps: 9 shift-tiles [dlt][j][136] bf16; tile dlt row j = x_{(j+dlt)&15}*x_j.
    //     row stride 272 B -> frag b128 reads uniform over 8 bank-slots.
    // hs: GEMM2 staging [16][520] bf16 (16640 B) -- ALIASES ps (dead by then).
    __shared__ __align__(16) unsigned char smem_raw[9 * 16 * 136 * 2];  // 39168 B
    bf16 (*ps)[16][136] = reinterpret_cast<bf16(*)[16][136]>(smem_raw);
    bf16 (*hs)[520]     = reinterpret_cast<bf16(*)[520]>(smem_raw);

    const int b    = blockIdx.x;
    const int tid  = threadIdx.x;
    const int wave = tid >> 6;    // 0..7
    const int lane = tid & 63;
    const int quad = lane >> 4;   // 0..3
    const int col  = lane & 15;   // 0..15

    // build-phase coordinates: thread owns (jrow, dq..dq+4)
    const int jrow = tid >> 5;          // 0..15
    const int dq   = (tid & 31) * 4;    // 0..124

    // ---- stage x_b into LDS (f32); keep own 4-float slice in regs ----
    f32x4 xj;
    {
        const float* src = x + (size_t)b * (AA * DD) + jrow * DD + dq;
        xj = *(const f32x4*)src;
        *(f32x4*)(&xs[jrow][dq]) = xj;
    }

    // ---- W1 fragments, register-resident (4n x 4kk x 16B = 64 regs) ----
    // Used as MFMA arg0 (A-operand): lane holds W1b[h = n*16+col][k-slice].
    bf16x8 w1f[4][4];
    // bias packed as bf16-hi pairs: 8 regs instead of 16 (frees 8 for srot)
    unsigned int bias_pk[8];
#pragma unroll
    for (int n = 0; n < 4; ++n) {
        int h = wave * 64 + n * 16 + col;
        f32x4 bv = *(const f32x4*)(b1 + wave * 64 + n * 16 + quad * 4);
        bias_pk[n * 2 + 0] = (__float_as_uint(bv[0]) >> 16) |
                             (__float_as_uint(bv[1]) & 0xFFFF0000u);
        bias_pk[n * 2 + 1] = (__float_as_uint(bv[2]) >> 16) |
                             (__float_as_uint(bv[3]) & 0xFFFF0000u);
#pragma unroll
        for (int kk = 0; kk < 4; ++kk)
            w1f[n][kk] = *(const bf16x8*)(W1b + h * DD + kk * 32 + quad * 8);
    }

    f32x4 hsum[4];   // aligned accumulator
    f32x4 srot[4];   // Horner accumulator for the rotated sum
#pragma unroll
    for (int n = 0; n < 4; ++n) { hsum[n] = splat4(0.f); srot[n] = splat4(0.f); }

    __syncthreads();   // xs complete

    // ---- build 9 shift tiles: ps[dlt][j][d] = bf16(x_{(j+dlt)&15}[d]*x_j[d]) ----
#pragma unroll
    for (int dlt = 0; dlt < 9; ++dlt) {
        f32x4 xi = *(f32x4*)(&xs[(jrow + dlt) & 15][dq]);
        bf16x4 pr;
#pragma unroll
        for (int e = 0; e < 4; ++e) pr[e] = (bf16)(xj[e] * xi[e]);
        *(bf16x4*)(&ps[dlt][jrow][dq]) = pr;
    }
    __syncthreads();   // all tiles ready; no barriers until GEMM2 staging

    // ---- GEMM1 over 9 shift tiles (SWAPPED operands: C rows=h, cols=j) ----
    // v_dlt = relu(W1 @ pair_dlt + b1); lane(q,c) holds v[h=base+n*16+q*4+r][j=c].
    // hsum[j]  = sum_{dlt=0..8} v_dlt[j]                     (aligned adds)
    // rotated  = sum_{dlt=1..7} v_dlt[(j-dlt)&15]            (tiles 16-dlt)
    // Horner over DESCENDING dlt: srot = v_dlt + ror1(srot) for dlt=7..1;
    // then hsum += ror1(srot). Branch-free steady state (uniform if only).
#pragma unroll 1
    for (int dlt = 8; dlt >= 0; --dlt) {
        const bf16* pbase = &ps[dlt][col][quad * 8];

        // af double-buffer: only 2 fragments live at once (8 regs, not 16)
        bf16x8 afA = *(const bf16x8*)(pbase);          // kk = 0
        bf16x8 afB = *(const bf16x8*)(pbase + 32);     // kk = 1

        f32x4 v[4];
#pragma unroll
        for (int n = 0; n < 4; ++n) {
            f32x4 bt;   // unpack bias just-in-time (4 shifts, transient regs)
            bt[0] = __uint_as_float(bias_pk[n * 2 + 0] << 16);
            bt[1] = __uint_as_float(bias_pk[n * 2 + 0] & 0xFFFF0000u);
            bt[2] = __uint_as_float(bias_pk[n * 2 + 1] << 16);
            bt[3] = __uint_as_float(bias_pk[n * 2 + 1] & 0xFFFF0000u);
            v[n] = __builtin_amdgcn_mfma_f32_16x16x32_bf16(
                w1f[n][0], afA, bt, 0, 0, 0);
        }
        afA = *(const bf16x8*)(pbase + 64);            // kk = 2
#pragma unroll
        for (int n = 0; n < 4; ++n)
            v[n] = __builtin_amdgcn_mfma_f32_16x16x32_bf16(
                w1f[n][1], afB, v[n], 0, 0, 0);
        afB = *(const bf16x8*)(pbase + 96);            // kk = 3
#pragma unroll
        for (int n = 0; n < 4; ++n)
            v[n] = __builtin_amdgcn_mfma_f32_16x16x32_bf16(
                w1f[n][2], afA, v[n], 0, 0, 0);
#pragma unroll
        for (int n = 0; n < 4; ++n)
            v[n] = __builtin_amdgcn_mfma_f32_16x16x32_bf16(
                w1f[n][3], afB, v[n], 0, 0, 0);

        // relu + aligned add
#pragma unroll
        for (int n = 0; n < 4; ++n)
#pragma unroll
            for (int r = 0; r < 4; ++r) {
                v[n][r] = fmaxf(v[n][r], 0.f);
                hsum[n][r] += v[n][r];
            }

        // Horner step (uniform branch; no switch -> prefetch hoisting intact)
        if (dlt >= 1 && dlt <= 7) {
#pragma unroll
            for (int n = 0; n < 4; ++n)
#pragma unroll
                for (int r = 0; r < 4; ++r)
                    srot[n][r] = v[n][r] + ror1_f32(srot[n][r]);
        }
    }

    // close the Horner chain: hsum += R(srot)
#pragma unroll
    for (int n = 0; n < 4; ++n)
#pragma unroll
        for (int r = 0; r < 4; ++r)
            hsum[n][r] += ror1_f32(srot[n][r]);

    __syncthreads();   // all ps reads done before hs overwrites the region

    // ---- hsum -> LDS (bf16) for GEMM2 A-operand re-layout ----
    // Transposed C layout: lane(q,c) holds hsum[j=c][h = w*64+n*16+q*4+r]
    // -> contiguous in h: one bf16x4 store per n.
#pragma unroll
    for (int n = 0; n < 4; ++n) {
        bf16x4 o;
#pragma unroll
        for (int r = 0; r < 4; ++r) o[r] = (bf16)hsum[n][r];
        *(bf16x4*)(&hs[col][wave * 64 + n * 16 + quad * 4]) = o;
    }

    __syncthreads();

    // ---- GEMM2: out[j,d] = hsum[j,:] @ W2^T + 16*b2 ----
    // M=16 (j), N=16 per wave (d = wave*16 + col), K=512 (h). W2b is [D,H].
    const int d = wave * 16 + col;
    f32x4 acc2 = splat4(16.f * b2[d]);

#pragma unroll
    for (int ks = 0; ks < 16; ++ks) {
        int h0 = ks * 32 + quad * 8;
        bf16x8 a2 = *(bf16x8*)(&hs[col][h0]);
        bf16x8 bw = *(const bf16x8*)(W2b + d * HH + h0);
        acc2 = __builtin_amdgcn_mfma_f32_16x16x32_bf16(a2, bw, acc2, 0, 0, 0);
    }

#pragma unroll
    for (int r = 0; r < 4; ++r) {
        int j = quad * 4 + r;
        out[(size_t)b * (AA * DD) + j * DD + d] = acc2[r];
    }
}

extern "C" void kernel_launch(void* const* d_in, const int* in_sizes, int n_in,
                              void* d_out, int out_size, void* d_ws, size_t ws_size,
                              hipStream_t stream)
{
    const float* x  = (const float*)d_in[0];  // [2048,16,128]
    const float* W1 = (const float*)d_in[1];  // [512,128]
    const float* b1 = (const float*)d_in[2];  // [512]
    const float* W2 = (const float*)d_in[3];  // [128,512]
    const float* b2 = (const float*)d_in[4];  // [128]
    float* out = (float*)d_out;

    bf16* wsb = (bf16*)d_ws;                  // 256 KB used
    convert_weights<<<128, 256, 0, stream>>>(W1, W2, wsb);

    const bf16* W1b = wsb;
    const bf16* W2b = wsb + (size_t)HH * DD;
    interact_kernel<<<BATCH, 512, 0, stream>>>(x, W1b, b1, W2b, b2, out);
}

// Round 11
// 148.303 us; speedup vs baseline: 1.4799x; 1.4799x over previous
//
#include <hip/hip_runtime.h>

// InternalInteraction: out[b,j,d] = sum_i [ relu((x_i*x_j)@W1^T + b1) @ W2^T + b2 ]
// Factored: hsum[b,j,h] = sum_i relu((x_i*x_j)@W1^T + b1); out = hsum@W2^T + 16*b2.
// B=2048, A=16, D=128, H=512. Storage fp32; MFMA in bf16.
//
// FINAL (round-14) = round-8 kernel verbatim (best verified: 87.2us interact,
// 146.7us total). Session ledger that pins this as the optimum:
//  - SYMMETRY CUT (r8, the one real win, 95->87us): pairs[i,j]=pairs[j,i] ->
//    compute only 9 shift tiles (dlt=(i-j)&15, dlt=0..8); tiles dlt and
//    16-dlt are equal row-rotated, so each relu'd tile dlt=1..7 is added
//    twice: aligned (register add) + rotated by dlt over the j-lane dim
//    (ds_bpermute, runtime idx). GEMM1 MFMA -41%, af reads -44%.
//    Swapped-operand MFMA (C rows=h, cols=j) makes the rotation pure-lane.
//  - The remaining ~18us (112 bpermute/wave on the LDS pipe) is BLOCKED by
//    a measured constraint web; every escape fails:
//      r9  Horner-DPP +16 regs @ (512,4)  -> spill (WRITE 16->95MB)
//      r10 same @ (512,2) 256-reg budget  -> 8 waves/CU starve (+18us)
//      r11 16 waves x 32h (regs free)     -> af traffic x2 (conflicts x1.64)
//      r12 switch-DPP (zero extra regs)   -> blocks af prefetch (+15us)
//      r13 Horner + packed-bias/af-2buf   -> spill anyway (WRITE 98MB)
//    Constraint web: bperm->VALU needs +16 VGPR; 16 waves/CU needs <=128
//    regs (r10: below 16 waves costs ~18us); r8 has ~0 reg slack (3MB
//    micro-spill already); af traffic ~ waves x tiles forbids wider
//    per-wave h-tiles (n=8 -> ~255 regs -> 8-wave tier -> starved).
//  - Scheduling levers all null on this kernel: occupancy 2x (r5: 0),
//    barrier removal 16->4 (r3->r5: 0), wave stagger + setprio (r6: -4%).
//    Pipe demands are additive: MFMA ~17 + VALU ~21 + LDS ~40 ~= 87us wall.
//  - Not a HW roofline (no pipe saturated); a measured local optimum.

#define BATCH 2048
#define AA 16
#define DD 128
#define HH 512

typedef __bf16 bf16;
typedef bf16  bf16x4 __attribute__((ext_vector_type(4)));
typedef bf16  bf16x8 __attribute__((ext_vector_type(8)));
typedef float f32x4  __attribute__((ext_vector_type(4)));

__device__ inline f32x4 splat4(float v) { f32x4 r = {v, v, v, v}; return r; }

// pull float from another lane: idx = source_lane * 4 (byte index)
__device__ inline float bperm_f32(int idx, float v) {
    return __int_as_float(__builtin_amdgcn_ds_bpermute(idx, __float_as_int(v)));
}

// ---- prologue: fp32 -> bf16 weight conversion into d_ws ----
// ws layout: [0, 65536)  = W1b (512x128 row-major bf16)
//            [65536, ..) = W2b (128x512 row-major bf16)
__global__ __launch_bounds__(256, 1)
void convert_weights(const float* __restrict__ W1,
                     const float* __restrict__ W2,
                     bf16* __restrict__ wsb)
{
    int t = blockIdx.x * 256 + threadIdx.x;      // 0..32767, 4 elems each
    f32x4 v = (t < 16384) ? *(const f32x4*)(W1 + 4 * t)
                          : *(const f32x4*)(W2 + 4 * (t - 16384));
    bf16x4 o;
    o[0] = (bf16)v[0]; o[1] = (bf16)v[1]; o[2] = (bf16)v[2]; o[3] = (bf16)v[3];
    *(bf16x4*)(wsb + 4 * t) = o;
}

// One block per batch. 512 threads = 8 waves; wave w owns H cols [w*64, w*64+64).
__global__ __launch_bounds__(512, 4)
void interact_kernel(const float* __restrict__ x,    // [B, A, D] fp32
                     const bf16*  __restrict__ W1b,  // [H, D] bf16 (from ws)
                     const float* __restrict__ b1,   // [H]
                     const bf16*  __restrict__ W2b,  // [D, H] bf16 (from ws)
                     const float* __restrict__ b2,   // [D]
                     float* __restrict__ out)        // [B, A, D] fp32
{
    // xs: x_b in f32, row stride 136 (544 B)
    __shared__ float xs[16][136];                               // 8704 B
    // ps: 9 shift-tiles [dlt][j][136] bf16; tile dlt row j = x_{(j+dlt)&15}*x_j.
    //     row stride 272 B -> frag b128 reads uniform over 8 bank-slots.
    // hs: GEMM2 staging [16][520] bf16 (16640 B) -- ALIASES ps (dead by then).
    __shared__ __align__(16) unsigned char smem_raw[9 * 16 * 136 * 2];  // 39168 B
    bf16 (*ps)[16][136] = reinterpret_cast<bf16(*)[16][136]>(smem_raw);
    bf16 (*hs)[520]     = reinterpret_cast<bf16(*)[520]>(smem_raw);

    const int b    = blockIdx.x;
    const int tid  = threadIdx.x;
    const int wave = tid >> 6;    // 0..7
    const int lane = tid & 63;
    const int quad = lane >> 4;   // 0..3
    const int col  = lane & 15;   // 0..15

    // build-phase coordinates: thread owns (jrow, dq..dq+4)
    const int jrow = tid >> 5;          // 0..15
    const int dq   = (tid & 31) * 4;    // 0..124

    // ---- stage x_b into LDS (f32); keep own 4-float slice in regs ----
    f32x4 xj;
    {
        const float* src = x + (size_t)b * (AA * DD) + jrow * DD + dq;
        xj = *(const f32x4*)src;
        *(f32x4*)(&xs[jrow][dq]) = xj;
    }

    // ---- W1 fragments, register-resident (4n x 4kk x 16B = 64 regs) ----
    // Used as MFMA arg0 (A-operand): lane holds W1b[h = n*16+col][k-slice].
    bf16x8 w1f[4][4];
    f32x4  bias4[4];   // C-seed: b1[h0 + quad*4 + r] per reg r (C rows = h now)
#pragma unroll
    for (int n = 0; n < 4; ++n) {
        int h    = wave * 64 + n * 16 + col;
        bias4[n] = *(const f32x4*)(b1 + wave * 64 + n * 16 + quad * 4);
#pragma unroll
        for (int kk = 0; kk < 4; ++kk)
            w1f[n][kk] = *(const bf16x8*)(W1b + h * DD + kk * 32 + quad * 8);
    }

    f32x4 hsum[4];
#pragma unroll
    for (int n = 0; n < 4; ++n) hsum[n] = splat4(0.f);

    __syncthreads();   // xs complete

    // ---- build 9 shift tiles: ps[dlt][j][d] = bf16(x_{(j+dlt)&15}[d]*x_j[d]) ----
#pragma unroll
    for (int dlt = 0; dlt < 9; ++dlt) {
        f32x4 xi = *(f32x4*)(&xs[(jrow + dlt) & 15][dq]);
        bf16x4 pr;
#pragma unroll
        for (int e = 0; e < 4; ++e) pr[e] = (bf16)(xj[e] * xi[e]);
        *(bf16x4*)(&ps[dlt][jrow][dq]) = pr;
    }
    __syncthreads();   // all tiles ready; no barriers until GEMM2 staging

    // ---- GEMM1 over 9 shift tiles (SWAPPED operands: C rows=h, cols=j) ----
    // arg0 = w1f (A rows = h-sub = col), arg1 = af (B cols = j = col).
    // C/D: lane(q,c) holds v[h = base + n*16 + q*4 + r][j = c].
    // hsum[j] = sum_{d=0..8} v_d[j] + sum_{d=1..7} v_d[(j-d)&15]; the second
    // term is a pure lane-rotation within the 16-lane col group -> one
    // runtime-indexed ds_bpermute per (n,r), same register. unroll 1!
#pragma unroll 1
    for (int dlt = 0; dlt < 9; ++dlt) {
        bf16x8 af[4];
#pragma unroll
        for (int kk = 0; kk < 4; ++kk)
            af[kk] = *(bf16x8*)(&ps[dlt][col][kk * 32 + quad * 8]);

        f32x4 v[4];
#pragma unroll
        for (int n = 0; n < 4; ++n)
            v[n] = __builtin_amdgcn_mfma_f32_16x16x32_bf16(
                w1f[n][0], af[0], bias4[n], 0, 0, 0);
#pragma unroll
        for (int kk = 1; kk < 4; ++kk)
#pragma unroll
            for (int n = 0; n < 4; ++n)
                v[n] = __builtin_amdgcn_mfma_f32_16x16x32_bf16(
                    w1f[n][kk], af[kk], v[n], 0, 0, 0);

        // relu in place
#pragma unroll
        for (int n = 0; n < 4; ++n)
#pragma unroll
            for (int r = 0; r < 4; ++r)
                v[n][r] = fmaxf(v[n][r], 0.f);

        // aligned add
#pragma unroll
        for (int n = 0; n < 4; ++n)
#pragma unroll
            for (int r = 0; r < 4; ++r)
                hsum[n][r] += v[n][r];

        // rotated add (tile 16-dlt): lane j takes lane (j-dlt)&15, same quad
        if (dlt >= 1 && dlt <= 7) {
            const int idx = ((quad << 4) | ((col - dlt) & 15)) << 2;
#pragma unroll
            for (int n = 0; n < 4; ++n)
#pragma unroll
                for (int r = 0; r < 4; ++r)
                    hsum[n][r] += bperm_f32(idx, v[n][r]);
        }
    }

    __syncthreads();   // all ps reads done before hs overwrites the region

    // ---- hsum -> LDS (bf16) for GEMM2 A-operand re-layout ----
    // Transposed C layout: lane(q,c) holds hsum[j=c][h = w*64+n*16+q*4+r]
    // -> contiguous in h: one bf16x4 store per n.
#pragma unroll
    for (int n = 0; n < 4; ++n) {
        bf16x4 o;
#pragma unroll
        for (int r = 0; r < 4; ++r) o[r] = (bf16)hsum[n][r];
        *(bf16x4*)(&hs[col][wave * 64 + n * 16 + quad * 4]) = o;
    }

    __syncthreads();

    // ---- GEMM2: out[j,d] = hsum[j,:] @ W2^T + 16*b2 ----
    // M=16 (j), N=16 per wave (d = wave*16 + col), K=512 (h). W2b is [D,H].
    const int d = wave * 16 + col;
    f32x4 acc2 = splat4(16.f * b2[d]);

#pragma unroll
    for (int ks = 0; ks < 16; ++ks) {
        int h0 = ks * 32 + quad * 8;
        bf16x8 a2 = *(bf16x8*)(&hs[col][h0]);
        bf16x8 bw = *(const bf16x8*)(W2b + d * HH + h0);
        acc2 = __builtin_amdgcn_mfma_f32_16x16x32_bf16(a2, bw, acc2, 0, 0, 0);
    }

#pragma unroll
    for (int r = 0; r < 4; ++r) {
        int j = quad * 4 + r;
        out[(size_t)b * (AA * DD) + j * DD + d] = acc2[r];
    }
}

extern "C" void kernel_launch(void* const* d_in, const int* in_sizes, int n_in,
                              void* d_out, int out_size, void* d_ws, size_t ws_size,
                              hipStream_t stream)
{
    const float* x  = (const float*)d_in[0];  // [2048,16,128]
    const float* W1 = (const float*)d_in[1];  // [512,128]
    const float* b1 = (const float*)d_in[2];  // [512]
    const float* W2 = (const float*)d_in[3];  // [128,512]
    const float* b2 = (const float*)d_in[4];  // [128]
    float* out = (float*)d_out;

    bf16* wsb = (bf16*)d_ws;                  // 256 KB used
    convert_weights<<<128, 256, 0, stream>>>(W1, W2, wsb);

    const bf16* W1b = wsb;
    const bf16* W2b = wsb + (size_t)HH * DD;
    interact_kernel<<<BATCH, 512, 0, stream>>>(x, W1b, b1, W2b, b2, out);
}